// Round 1
// baseline (878.608 us; speedup 1.0000x reference)
//
#include <hip/hip_runtime.h>
#include <math.h>

#define NN 100000
#define NE 3200000
#define HID 16

// ---------------- graph normalization ----------------

__global__ void k_deg_init(float* __restrict__ deg, float* __restrict__ scal) {
    int i = blockIdx.x * 256 + threadIdx.x;
    if (i < NN) deg[i] = 1.0f;                 // self-loop weight
    if (blockIdx.x == 0 && threadIdx.x < 32) scal[threadIdx.x] = 0.0f;
}

__global__ void k_deg_acc(const int* __restrict__ dst, const float* __restrict__ w,
                          float* __restrict__ deg) {
    int e = blockIdx.x * 256 + threadIdx.x;
    if (e < NE) atomicAdd(&deg[dst[e]], w[e]);
}

__global__ void k_dinv(float* __restrict__ deg) {
    int i = blockIdx.x * 256 + threadIdx.x;
    if (i < NN) {
        float d = deg[i];
        deg[i] = (d > 0.0f) ? rsqrtf(d) : 0.0f;   // in-place deg -> dinv
    }
}

__global__ void k_norm(const int* __restrict__ src, const int* __restrict__ dst,
                       const float* __restrict__ w, const float* __restrict__ dinv,
                       float* __restrict__ norm) {
    int e = blockIdx.x * 256 + threadIdx.x;
    if (e < NE) norm[e] = dinv[src[e]] * w[e] * dinv[dst[e]];
}

// ---------------- dense transforms ----------------

// h[i][f] = sum_k x[i][k] * W[f][k]   (64 -> 16)
__global__ void k_xform64(const float* __restrict__ x, const float* __restrict__ W,
                          float* __restrict__ out) {
    __shared__ float Ws[16 * 64];
    for (int t = threadIdx.x; t < 16 * 64; t += 256) Ws[t] = W[t];
    __syncthreads();
    int i = blockIdx.x * 256 + threadIdx.x;
    if (i >= NN) return;
    const float4* xr = (const float4*)(x + (long long)i * 64);
    float acc[16];
#pragma unroll
    for (int f = 0; f < 16; ++f) acc[f] = 0.0f;
#pragma unroll
    for (int k4 = 0; k4 < 16; ++k4) {
        float4 xv = xr[k4];
#pragma unroll
        for (int f = 0; f < 16; ++f) {
            float4 wv = ((const float4*)(Ws + f * 64))[k4];
            acc[f] += xv.x * wv.x + xv.y * wv.y + xv.z * wv.z + xv.w * wv.w;
        }
    }
    float4* o = (float4*)(out + (long long)i * 16);
#pragma unroll
    for (int q = 0; q < 4; ++q)
        o[q] = make_float4(acc[4 * q + 0], acc[4 * q + 1], acc[4 * q + 2], acc[4 * q + 3]);
}

// out[i][f] = sum_k relu(in[i][k]) * W[f][k]   (16 -> 16, relu fused on input)
__global__ void k_xform16(const float* __restrict__ in, const float* __restrict__ W,
                          float* __restrict__ out) {
    __shared__ float Ws[256];
    if (threadIdx.x < 256) Ws[threadIdx.x] = W[threadIdx.x];
    __syncthreads();
    int i = blockIdx.x * 256 + threadIdx.x;
    if (i >= NN) return;
    float xv[16];
    const float4* r = (const float4*)(in + (long long)i * 16);
#pragma unroll
    for (int k4 = 0; k4 < 4; ++k4) {
        float4 v = r[k4];
        xv[4 * k4 + 0] = fmaxf(v.x, 0.0f);
        xv[4 * k4 + 1] = fmaxf(v.y, 0.0f);
        xv[4 * k4 + 2] = fmaxf(v.z, 0.0f);
        xv[4 * k4 + 3] = fmaxf(v.w, 0.0f);
    }
    float acc[16];
#pragma unroll
    for (int f = 0; f < 16; ++f) {
        float a = 0.0f;
#pragma unroll
        for (int k = 0; k < 16; ++k) a += xv[k] * Ws[f * 16 + k];
        acc[f] = a;
    }
    float4* o = (float4*)(out + (long long)i * 16);
#pragma unroll
    for (int q = 0; q < 4; ++q)
        o[q] = make_float4(acc[4 * q + 0], acc[4 * q + 1], acc[4 * q + 2], acc[4 * q + 3]);
}

// clin[i] = sum_k relu(in[i][k]) * W3[k]   (16 -> 1, relu fused)
__global__ void k_xform_c(const float* __restrict__ in, const float* __restrict__ W3,
                          float* __restrict__ clin) {
    int i = blockIdx.x * 256 + threadIdx.x;
    if (i >= NN) return;
    float acc = 0.0f;
#pragma unroll
    for (int k = 0; k < 16; ++k) acc += fmaxf(in[i * 16 + k], 0.0f) * W3[k];
    clin[i] = acc;
}

// ---------------- aggregation ----------------

// out[i][f] = b[f] + dinv[i]^2 * h[i][f]
__global__ void k_agg_init(const float* __restrict__ h, const float* __restrict__ dinv,
                           const float* __restrict__ b, float* __restrict__ out) {
    int gid = blockIdx.x * 256 + threadIdx.x;   // over NN*16
    if (gid >= NN * 16) return;
    int i = gid >> 4, f = gid & 15;
    float di = dinv[i];
    out[gid] = b[f] + di * di * h[gid];
}

// out[dst][f] += norm[e] * h[src][f]
__global__ void k_agg_edge(const int* __restrict__ src, const int* __restrict__ dst,
                           const float* __restrict__ norm, const float* __restrict__ h,
                           float* __restrict__ out) {
    int gid = blockIdx.x * 256 + threadIdx.x;   // over NE*16 = 51.2M (< 2^31)
    if (gid >= NE * 16) return;
    int e = gid >> 4, f = gid & 15;
    int s = src[e], d = dst[e];
    atomicAdd(&out[d * 16 + f], norm[e] * h[s * 16 + f]);
}

__global__ void k_aggc_init(const float* __restrict__ clin, const float* __restrict__ dinv,
                            const float* __restrict__ b3, float* __restrict__ c) {
    int i = blockIdx.x * 256 + threadIdx.x;
    if (i < NN) {
        float di = dinv[i];
        c[i] = b3[0] + di * di * clin[i];
    }
}

__global__ void k_aggc_edge(const int* __restrict__ src, const int* __restrict__ dst,
                            const float* __restrict__ norm, const float* __restrict__ clin,
                            float* __restrict__ c) {
    int e = blockIdx.x * 256 + threadIdx.x;
    if (e < NE) atomicAdd(&c[dst[e]], norm[e] * clin[src[e]]);
}

// ---------------- pooling (mean of relu(h2)) ----------------

__global__ void k_pool(const float* __restrict__ h, float* __restrict__ hsum) {
    __shared__ float lds[256];
    int f = threadIdx.x & 15;
    int row0 = (blockIdx.x * 256 + threadIdx.x) >> 4;
    int stride = (gridDim.x * 256) >> 4;
    float acc = 0.0f;
    for (int i = row0; i < NN; i += stride) acc += fmaxf(h[i * 16 + f], 0.0f);
    lds[threadIdx.x] = acc;
    __syncthreads();
    for (int s = 128; s >= 16; s >>= 1) {
        if (threadIdx.x < s) lds[threadIdx.x] += lds[threadIdx.x + s];
        __syncthreads();
    }
    if (threadIdx.x < 16) atomicAdd(&hsum[threadIdx.x], lds[threadIdx.x]);
}

// ---------------- softmax ----------------

__device__ __forceinline__ unsigned fkey(float x) {
    unsigned b = __float_as_uint(x);
    return (b & 0x80000000u) ? ~b : (b | 0x80000000u);
}
__device__ __forceinline__ float fdecode(unsigned u) {
    unsigned b = (u & 0x80000000u) ? (u & 0x7FFFFFFFu) : ~u;
    return __uint_as_float(b);
}

__global__ void k_max(const float* __restrict__ c, unsigned* __restrict__ maxkey) {
    __shared__ float lds[256];
    float m = -INFINITY;
    for (int i = blockIdx.x * 256 + threadIdx.x; i < NN; i += gridDim.x * 256)
        m = fmaxf(m, c[i]);
    lds[threadIdx.x] = m;
    __syncthreads();
    for (int s = 128; s > 0; s >>= 1) {
        if (threadIdx.x < s) lds[threadIdx.x] = fmaxf(lds[threadIdx.x], lds[threadIdx.x + s]);
        __syncthreads();
    }
    if (threadIdx.x == 0) atomicMax(maxkey, fkey(lds[0]));
}

__global__ void k_exp(const float* __restrict__ c, const unsigned* __restrict__ maxkey,
                      float* __restrict__ outp, float* __restrict__ sumexp) {
    __shared__ float lds[256];
    float mx = fdecode(*maxkey);
    float s = 0.0f;
    for (int i = blockIdx.x * 256 + threadIdx.x; i < NN; i += gridDim.x * 256) {
        float p = expf(c[i] - mx);
        outp[i] = p;
        s += p;
    }
    lds[threadIdx.x] = s;
    __syncthreads();
    for (int t = 128; t > 0; t >>= 1) {
        if (threadIdx.x < t) lds[threadIdx.x] += lds[threadIdx.x + t];
        __syncthreads();
    }
    if (threadIdx.x == 0) atomicAdd(sumexp, lds[0]);
}

__global__ void k_final(float* __restrict__ out, const float* __restrict__ sumexp,
                        const float* __restrict__ hsum, const float* __restrict__ A2w,
                        const float* __restrict__ A2b) {
    float inv = 1.0f / (*sumexp);
    for (int i = blockIdx.x * 256 + threadIdx.x; i < NN; i += gridDim.x * 256)
        out[i] *= inv;
    if (blockIdx.x == 0 && threadIdx.x == 0) {
        float v = 0.0f;
#pragma unroll
        for (int f = 0; f < 16; ++f) v += hsum[f] * (1.0f / (float)NN) * A2w[f];
        out[NN] = v + A2b[0];
    }
}

// ---------------- launch ----------------

extern "C" void kernel_launch(void* const* d_in, const int* in_sizes, int n_in,
                              void* d_out, int out_size, void* d_ws, size_t ws_size,
                              hipStream_t stream) {
    const float* x   = (const float*)d_in[0];
    const int*   src = (const int*)d_in[1];            // edges row 0
    const int*   dst = ((const int*)d_in[1]) + NE;     // edges row 1
    const float* w   = (const float*)d_in[2];
    const float* W1  = (const float*)d_in[3];
    const float* b1  = (const float*)d_in[4];
    const float* W2  = (const float*)d_in[5];
    const float* b2  = (const float*)d_in[6];
    const float* W3  = (const float*)d_in[7];
    const float* b3  = (const float*)d_in[8];
    const float* A2w = (const float*)d_in[9];
    const float* A2b = (const float*)d_in[10];
    float* out = (float*)d_out;

    float* ws   = (float*)d_ws;
    float* norm = ws;                    // NE
    float* dinv = norm + NE;             // NN  (deg, then dinv in place)
    float* bufA = dinv + NN;             // NN*16
    float* bufB = bufA + NN * 16;        // NN*16
    float* bufC = bufB + NN * 16;        // NN*16
    float* clin = bufC + NN * 16;        // NN
    float* cbuf = clin + NN;             // NN
    float* scal = cbuf + NN;             // [0]=maxkey(u32) [1]=sumexp [2..17]=hsum

    const int NB_N   = (NN + 255) / 256;         // 391
    const int NB_E   = (NE + 255) / 256;         // 12500
    const int NB_NF  = (NN * 16) / 256;          // 6250
    const int NB_EF  = (NE * 16) / 256;          // 200000

    // graph norm
    k_deg_init<<<NB_N, 256, 0, stream>>>(dinv, scal);
    k_deg_acc<<<NB_E, 256, 0, stream>>>(dst, w, dinv);
    k_dinv<<<NB_N, 256, 0, stream>>>(dinv);
    k_norm<<<NB_E, 256, 0, stream>>>(src, dst, w, dinv, norm);

    // layer 1: x[100k,64] -> bufB[100k,16]
    k_xform64<<<NB_N, 256, 0, stream>>>(x, W1, bufA);
    k_agg_init<<<NB_NF, 256, 0, stream>>>(bufA, dinv, b1, bufB);
    k_agg_edge<<<NB_EF, 256, 0, stream>>>(src, dst, norm, bufA, bufB);

    // layer 2: relu(bufB) -> bufA[100k,16]   (relu fused into transform)
    k_xform16<<<NB_N, 256, 0, stream>>>(bufB, W2, bufC);
    k_agg_init<<<NB_NF, 256, 0, stream>>>(bufC, dinv, b2, bufA);
    k_agg_edge<<<NB_EF, 256, 0, stream>>>(src, dst, norm, bufC, bufA);

    // layer 3: relu(bufA) -> cbuf[100k]; pooling of relu(bufA)
    k_xform_c<<<NB_N, 256, 0, stream>>>(bufA, W3, clin);
    k_pool<<<512, 256, 0, stream>>>(bufA, scal + 2);
    k_aggc_init<<<NB_N, 256, 0, stream>>>(clin, dinv, b3, cbuf);
    k_aggc_edge<<<NB_E, 256, 0, stream>>>(src, dst, norm, clin, cbuf);

    // softmax + value
    k_max<<<512, 256, 0, stream>>>(cbuf, (unsigned*)scal);
    k_exp<<<512, 256, 0, stream>>>(cbuf, (const unsigned*)scal, out, scal + 1);
    k_final<<<512, 256, 0, stream>>>(out, scal + 1, scal + 2, A2w, A2b);
}